// Round 1
// baseline (36.851 us; speedup 1.0000x reference)
//
#include <hip/hip_runtime.h>

// StructuredReadout: out[r, :] = node_states[idx[r], :]
// node_states: [N_NODES=1e6, D=256] f32, idx: [R=1e5] int, out: [R, 256] f32.
//
// Strategy: one 64-lane wave per row. Each lane moves one float4 (16B), so a
// wave transfers exactly one 1 KiB row with full coalescing on load and store.
// Row index is wave-uniform -> single broadcast load per wave.

__global__ __launch_bounds__(256) void StructuredReadout_47287589929655_kernel(
    const float4* __restrict__ src,   // node_states viewed as [N, 64] float4
    const int* __restrict__ idx,      // readout indices [R]
    float4* __restrict__ dst,         // out viewed as [R, 64] float4
    int total_f4)                     // R * 64
{
    int gid = blockIdx.x * blockDim.x + threadIdx.x;
    if (gid >= total_f4) return;
    int r = gid >> 6;        // output row (wave-uniform: 64 lanes per row)
    int c = gid & 63;        // float4 column within row
    long long srow = (long long)idx[r];
    dst[gid] = src[srow * 64 + c];
}

extern "C" void kernel_launch(void* const* d_in, const int* in_sizes, int n_in,
                              void* d_out, int out_size, void* d_ws, size_t ws_size,
                              hipStream_t stream) {
    const float4* src = (const float4*)d_in[0];   // node_states [1e6 * 256] f32
    const int*    idx = (const int*)d_in[1];      // readout_indices [1e5]
    float4*       dst = (float4*)d_out;           // [1e5 * 256] f32

    const int R = in_sizes[1];          // 100,000
    const int total_f4 = R * 64;        // one float4 per thread
    const int block = 256;
    const int grid = (total_f4 + block - 1) / block;

    StructuredReadout_47287589929655_kernel<<<grid, block, 0, stream>>>(
        src, idx, dst, total_f4);
}

// Round 3
// 35.957 us; speedup vs baseline: 1.0249x; 1.0249x over previous
//
#include <hip/hip_runtime.h>

// StructuredReadout: out[r, :] = node_states[idx[r], :]
// node_states: [N=1e6, D=256] f32 (1 GiB), idx: [R=1e5] int, out: [R, 256] f32.
//
// One 64-lane wave moves one 1 KiB row (16 B per lane), fully coalesced.
// Grid-stride with 4-way independent unroll: 4 gather loads in flight per
// thread before any store -> 4x VMEM MLP to cover random HBM-miss latency.
// Non-temporal stores: the 102 MB output is written once and never re-read.
// Use clang ext_vector_type, not HIP_vector_type, so the nontemporal builtin
// accepts the pointer (compiles to global_store_dwordx4 nt).

typedef float f32x4 __attribute__((ext_vector_type(4)));

__global__ __launch_bounds__(256) void StructuredReadout_47287589929655_kernel(
    const f32x4* __restrict__ src,    // node_states as [N, 64] f32x4
    const int* __restrict__ idx,      // readout indices [R]
    f32x4* __restrict__ dst,          // out as [R, 64] f32x4
    int total_f4)                     // R * 64
{
    const int S   = gridDim.x * blockDim.x;
    const int gid = blockIdx.x * blockDim.x + threadIdx.x;

    int g0 = gid, g1 = gid + S, g2 = gid + 2 * S, g3 = gid + 3 * S;

    if (g3 < total_f4) {
        // Fast path: 4 independent gathers issued before any store.
        long long r0 = idx[g0 >> 6], r1 = idx[g1 >> 6];
        long long r2 = idx[g2 >> 6], r3 = idx[g3 >> 6];
        f32x4 v0 = src[r0 * 64 + (g0 & 63)];
        f32x4 v1 = src[r1 * 64 + (g1 & 63)];
        f32x4 v2 = src[r2 * 64 + (g2 & 63)];
        f32x4 v3 = src[r3 * 64 + (g3 & 63)];
        __builtin_nontemporal_store(v0, &dst[g0]);
        __builtin_nontemporal_store(v1, &dst[g1]);
        __builtin_nontemporal_store(v2, &dst[g2]);
        __builtin_nontemporal_store(v3, &dst[g3]);
    } else {
        for (int g = g0; g < total_f4; g += S) {
            long long r = idx[g >> 6];
            f32x4 v = src[r * 64 + (g & 63)];
            __builtin_nontemporal_store(v, &dst[g]);
        }
    }
}

extern "C" void kernel_launch(void* const* d_in, const int* in_sizes, int n_in,
                              void* d_out, int out_size, void* d_ws, size_t ws_size,
                              hipStream_t stream) {
    const f32x4* src = (const f32x4*)d_in[0];     // node_states [1e6 * 256] f32
    const int*   idx = (const int*)d_in[1];       // readout_indices [1e5]
    f32x4*       dst = (f32x4*)d_out;             // [1e5 * 256] f32

    const int R = in_sizes[1];          // 100,000
    const int total_f4 = R * 64;        // 6.4M 16B moves
    const int block = 256;
    // 4 f32x4 per thread; grid covers total in one 4-deep stride pass.
    int grid = (total_f4 + block * 4 - 1) / (block * 4);   // 6250
    if (grid < 1) grid = 1;

    StructuredReadout_47287589929655_kernel<<<grid, block, 0, stream>>>(
        src, idx, dst, total_f4);
}